// Round 1
// baseline (137.967 us; speedup 1.0000x reference)
//
#include <hip/hip_runtime.h>

// S4D real: y[l,c] = sum_s w[c,s] * h_s[l],  h_s[l] = x[l,c] + r[c,s]*h_s[l-1]
// Blocked parallel scan over L: local chunk scan -> carry prefix -> seeded re-scan.

namespace {

constexpr int L_ = 4096;
constexpr int CH_ = 512;
constexpr int S_ = 64;
constexpr float DT = 1.0f / 4096.0f;

// ---------------- Kernel A: local chunk-end states (zero carry-in) ----------
// grid = (CH/64, NC), block = 64. lane -> channel. carry layout [k][s][c].
template <int T>
__global__ __launch_bounds__(64) void k_local(const float* __restrict__ x,
                                              const float* __restrict__ lognegA,
                                              float* __restrict__ carry) {
  const int c = blockIdx.x * 64 + threadIdx.x;
  const int k = blockIdx.y;

  float r[S_], h[S_];
  const float* la = lognegA + c * S_;
#pragma unroll
  for (int s = 0; s < S_; ++s) {
    r[s] = expf(-expf(la[s]) * DT);
    h[s] = 0.0f;
  }

  const float* xp = x + (size_t)k * T * CH_ + c;
#pragma unroll 2
  for (int l = 0; l < T; ++l) {
    const float xv = xp[l * CH_];
#pragma unroll
    for (int s = 0; s < S_; ++s) h[s] = fmaf(r[s], h[s], xv);
  }

  float* cp = carry + (size_t)k * (S_ * CH_) + c;
#pragma unroll
  for (int s = 0; s < S_; ++s) cp[s * CH_] = h[s];
}

// ---------------- Kernel B: sequential carry prefix over chunks -------------
// One thread per (c,s). In-place: carry[k] becomes carry-IN of chunk k.
__global__ void k_combine(const float* __restrict__ lognegA,
                          float* __restrict__ carry, int T, int NC) {
  const int tid = blockIdx.x * blockDim.x + threadIdx.x;  // = s*CH + c
  const int s = tid >> 9;          // / CH_
  const int c = tid & (CH_ - 1);   // % CH_

  const float r = expf(-expf(lognegA[c * S_ + s]) * DT);
  float rT = r;
  for (int t = 1; t < T; t <<= 1) rT *= rT;  // r^T (T is a power of two)

  float state = 0.0f;  // carry-in of chunk 0
  for (int k = 0; k < NC; ++k) {
    float* p = carry + (size_t)k * (S_ * CH_) + tid;
    const float le = *p;            // local end of chunk k
    *p = state;                     // carry-in of chunk k
    state = fmaf(rT, state, le);    // carry-in of chunk k+1
  }
}

// ---------------- Kernel C: seeded re-scan + output -------------------------
template <int T, bool USE_CARRY>
__global__ __launch_bounds__(64) void k_scan_out(const float* __restrict__ x,
                                                 const float* __restrict__ lognegA,
                                                 const float* __restrict__ B,
                                                 const float* __restrict__ C,
                                                 const float* __restrict__ carry,
                                                 float* __restrict__ y) {
  const int c = blockIdx.x * 64 + threadIdx.x;
  const int k = blockIdx.y;

  float r[S_], w[S_], h[S_];
#pragma unroll
  for (int s = 0; s < S_; ++s) {
    const int i = c * S_ + s;
    const float A = -expf(lognegA[i]);
    const float rv = expf(A * DT);
    r[s] = rv;
    w[s] = C[i] * ((rv - 1.0f) * B[i] / A);   // C * Bd
    h[s] = USE_CARRY ? carry[((size_t)k * S_ + s) * CH_ + c] : 0.0f;
  }

  const float* xp = x + (size_t)k * T * CH_ + c;
  float* yp = y + (size_t)k * T * CH_ + c;

  for (int l = 0; l < T; ++l) {
    const float xv = xp[l * CH_];
    float acc[8] = {0, 0, 0, 0, 0, 0, 0, 0};
#pragma unroll
    for (int s = 0; s < S_; ++s) {
      h[s] = fmaf(r[s], h[s], xv);
      acc[s & 7] = fmaf(w[s], h[s], acc[s & 7]);
    }
    const float t0 = ((acc[0] + acc[4]) + (acc[2] + acc[6])) +
                     ((acc[1] + acc[5]) + (acc[3] + acc[7]));
    yp[l * CH_] = t0;
  }
}

template <int T>
void launch_all(const float* x, const float* la, const float* B, const float* C,
                float* carry, float* y, hipStream_t stream) {
  constexpr int NC = L_ / T;
  dim3 g(CH_ / 64, NC);
  if (NC > 1) {
    k_local<T><<<g, 64, 0, stream>>>(x, la, carry);
    k_combine<<<(CH_ * S_) / 256, 256, 0, stream>>>(la, carry, T, NC);
    k_scan_out<T, true><<<g, 64, 0, stream>>>(x, la, B, C, carry, y);
  } else {
    k_scan_out<T, false><<<g, 64, 0, stream>>>(x, la, B, C, carry, y);
  }
}

}  // namespace

extern "C" void kernel_launch(void* const* d_in, const int* in_sizes, int n_in,
                              void* d_out, int out_size, void* d_ws, size_t ws_size,
                              hipStream_t stream) {
  const float* x = (const float*)d_in[0];
  const float* la = (const float*)d_in[1];
  const float* B = (const float*)d_in[2];
  const float* C = (const float*)d_in[3];
  float* y = (float*)d_out;
  float* carry = (float*)d_ws;

  // Pick NC (power of two) so the carry buffer fits in workspace.
  int NC = 128;
  while (NC > 1 && (size_t)NC * S_ * CH_ * sizeof(float) > ws_size) NC >>= 1;

  switch (L_ / NC) {
    case 32:   launch_all<32>(x, la, B, C, carry, y, stream); break;
    case 64:   launch_all<64>(x, la, B, C, carry, y, stream); break;
    case 128:  launch_all<128>(x, la, B, C, carry, y, stream); break;
    case 256:  launch_all<256>(x, la, B, C, carry, y, stream); break;
    case 512:  launch_all<512>(x, la, B, C, carry, y, stream); break;
    case 1024: launch_all<1024>(x, la, B, C, carry, y, stream); break;
    case 2048: launch_all<2048>(x, la, B, C, carry, y, stream); break;
    default:   launch_all<4096>(x, la, B, C, carry, y, stream); break;
  }
}

// Round 2
// 95.852 us; speedup vs baseline: 1.4394x; 1.4394x over previous
//
#include <hip/hip_runtime.h>

// S4D real: y[l,c] = sum_s w[c,s] * h_s[l],  h_s[l] = x[l,c] + r[c,s]*h_s[l-1]
// Blocked parallel scan over L:
//   k_params : precompute r = exp(A*dt), w = C*Bd in coalesced [s][c] layout
//   k_local  : per-chunk scan with zero carry, store chunk-end states
//   k_combine: carry prefix over chunks (batched loads -> register prefix)
//   k_scan_out: seeded re-scan + y = sum_s w*h

namespace {

constexpr int L_ = 4096;
constexpr int CH_ = 512;
constexpr int S_ = 64;
constexpr float DT = 1.0f / 4096.0f;
constexpr int SC = S_ * CH_;  // 32768

// ---------------- Kernel P: parameter precompute ----------------------------
// One thread per (s,c); tid = s*CH + c. Gathers lognegA/B/C ([c][s] layout),
// writes r/w in [s][c] layout so scan kernels load them coalesced.
__global__ void k_params(const float* __restrict__ lognegA,
                         const float* __restrict__ B,
                         const float* __restrict__ C,
                         float* __restrict__ rt, float* __restrict__ wt) {
  const int tid = blockIdx.x * blockDim.x + threadIdx.x;  // s*CH + c
  const int s = tid >> 9;
  const int c = tid & (CH_ - 1);
  const int i = c * S_ + s;
  const float A = -expf(lognegA[i]);
  const float r = expf(A * DT);
  rt[tid] = r;
  wt[tid] = C[i] * ((r - 1.0f) * B[i] / A);
}

// ---------------- Kernel A: local chunk-end states (zero carry-in) ----------
// grid = (CH/64, NC), block = 64. lane -> channel. carry layout [k][s][c].
template <int T>
__global__ __launch_bounds__(64) void k_local(const float* __restrict__ x,
                                              const float* __restrict__ rt,
                                              float* __restrict__ carry) {
  const int c = blockIdx.x * 64 + threadIdx.x;
  const int k = blockIdx.y;

  float r[S_], h[S_];
#pragma unroll
  for (int s = 0; s < S_; ++s) {
    r[s] = rt[s * CH_ + c];   // coalesced: lanes read contiguous c
    h[s] = 0.0f;
  }

  const float* xp = x + (size_t)k * T * CH_ + c;
#pragma unroll 4
  for (int l = 0; l < T; ++l) {
    const float xv = xp[l * CH_];
#pragma unroll
    for (int s = 0; s < S_; ++s) h[s] = fmaf(r[s], h[s], xv);
  }

  float* cp = carry + (size_t)k * SC + c;
#pragma unroll
  for (int s = 0; s < S_; ++s) cp[s * CH_] = h[s];
}

// ---------------- Kernel B: carry prefix over chunks ------------------------
// One thread per (s,c). In-place: carry[k] becomes carry-IN of chunk k.
// Loads are independent of the fma chain -> batch them to break the
// 128-step global-latency serialization.
template <int T, int NC>
__global__ void k_combine(const float* __restrict__ rt,
                          float* __restrict__ carry) {
  const int tid = blockIdx.x * blockDim.x + threadIdx.x;  // s*CH + c

  const float r = rt[tid];
  float rT = r;
#pragma unroll
  for (int t = 1; t < T; t <<= 1) rT *= rT;  // r^T (T is a power of two)

  constexpr int BATCH = (NC < 32) ? NC : 32;
  float state = 0.0f;  // carry-in of chunk 0
  for (int kb = 0; kb < NC; kb += BATCH) {
    float v[BATCH];
#pragma unroll
    for (int j = 0; j < BATCH; ++j) v[j] = carry[(size_t)(kb + j) * SC + tid];
#pragma unroll
    for (int j = 0; j < BATCH; ++j) {
      const float le = v[j];
      v[j] = state;                 // carry-in of chunk kb+j
      state = fmaf(rT, state, le);  // carry-in of next chunk
    }
#pragma unroll
    for (int j = 0; j < BATCH; ++j) carry[(size_t)(kb + j) * SC + tid] = v[j];
  }
}

// ---------------- Kernel C: seeded re-scan + output -------------------------
template <int T, bool USE_CARRY>
__global__ __launch_bounds__(64) void k_scan_out(const float* __restrict__ x,
                                                 const float* __restrict__ rt,
                                                 const float* __restrict__ wt,
                                                 const float* __restrict__ carry,
                                                 float* __restrict__ y) {
  const int c = blockIdx.x * 64 + threadIdx.x;
  const int k = blockIdx.y;

  float r[S_], w[S_], h[S_];
#pragma unroll
  for (int s = 0; s < S_; ++s) {
    r[s] = rt[s * CH_ + c];
    w[s] = wt[s * CH_ + c];
    h[s] = USE_CARRY ? carry[(size_t)k * SC + s * CH_ + c] : 0.0f;
  }

  const float* xp = x + (size_t)k * T * CH_ + c;
  float* yp = y + (size_t)k * T * CH_ + c;

#pragma unroll 4
  for (int l = 0; l < T; ++l) {
    const float xv = xp[l * CH_];
    float acc[8] = {0, 0, 0, 0, 0, 0, 0, 0};
#pragma unroll
    for (int s = 0; s < S_; ++s) {
      h[s] = fmaf(r[s], h[s], xv);
      acc[s & 7] = fmaf(w[s], h[s], acc[s & 7]);
    }
    yp[l * CH_] = ((acc[0] + acc[4]) + (acc[2] + acc[6])) +
                  ((acc[1] + acc[5]) + (acc[3] + acc[7]));
  }
}

template <int T>
void launch_all(const float* x, const float* la, const float* B, const float* C,
                float* ws, float* y, hipStream_t stream) {
  constexpr int NC = L_ / T;
  float* carry = ws;
  float* rt = ws + (size_t)NC * SC;
  float* wt = rt + SC;

  k_params<<<SC / 256, 256, 0, stream>>>(la, B, C, rt, wt);
  dim3 g(CH_ / 64, NC);
  if (NC > 1) {
    k_local<T><<<g, 64, 0, stream>>>(x, rt, carry);
    k_combine<T, NC><<<SC / 256, 256, 0, stream>>>(rt, carry);
    k_scan_out<T, true><<<g, 64, 0, stream>>>(x, rt, wt, carry, y);
  } else {
    k_scan_out<T, false><<<g, 64, 0, stream>>>(x, rt, wt, carry, y);
  }
}

}  // namespace

extern "C" void kernel_launch(void* const* d_in, const int* in_sizes, int n_in,
                              void* d_out, int out_size, void* d_ws, size_t ws_size,
                              hipStream_t stream) {
  const float* x = (const float*)d_in[0];
  const float* la = (const float*)d_in[1];
  const float* B = (const float*)d_in[2];
  const float* C = (const float*)d_in[3];
  float* y = (float*)d_out;
  float* ws = (float*)d_ws;

  // Pick NC (power of two) so carry + r + w fit in workspace.
  int NC = 128;
  while (NC > 1 &&
         ((size_t)NC * SC + 2 * SC) * sizeof(float) > ws_size) NC >>= 1;

  switch (L_ / NC) {
    case 32:   launch_all<32>(x, la, B, C, ws, y, stream); break;
    case 64:   launch_all<64>(x, la, B, C, ws, y, stream); break;
    case 128:  launch_all<128>(x, la, B, C, ws, y, stream); break;
    case 256:  launch_all<256>(x, la, B, C, ws, y, stream); break;
    case 512:  launch_all<512>(x, la, B, C, ws, y, stream); break;
    case 1024: launch_all<1024>(x, la, B, C, ws, y, stream); break;
    case 2048: launch_all<2048>(x, la, B, C, ws, y, stream); break;
    default:   launch_all<4096>(x, la, B, C, ws, y, stream); break;
  }
}